// Round 1
// baseline (281.860 us; speedup 1.0000x reference)
//
#include <hip/hip_runtime.h>

#define B_SZ 16384
#define DIN  1024
#define HID  512
#define COMP 64

typedef __bf16 bf16_t;
typedef __bf16 bf16x4 __attribute__((ext_vector_type(4)));
typedef __bf16 bf16x8 __attribute__((ext_vector_type(8)));
typedef float  f32x4  __attribute__((ext_vector_type(4)));

// ---------------------------------------------------------------------------
// transpose-convert: out[n][k] = (bf16) in[k][n].  grid.z selects A/B pair.
// ---------------------------------------------------------------------------
__global__ __launch_bounds__(256) void k_transpose(
    const float* __restrict__ inA, bf16_t* __restrict__ outA,
    const float* __restrict__ inB, bf16_t* __restrict__ outB,
    int K, int N)
{
    const float* in  = blockIdx.z ? inB  : inA;
    bf16_t*      out = blockIdx.z ? outB : outA;
    __shared__ float tile[32][33];
    const int tx = threadIdx.x, ty = threadIdx.y;
    const int n0 = blockIdx.x * 32, k0 = blockIdx.y * 32;
    #pragma unroll
    for (int i = 0; i < 4; i++)
        tile[ty + i * 8][tx] = in[(size_t)(k0 + ty + i * 8) * N + n0 + tx];
    __syncthreads();
    #pragma unroll
    for (int i = 0; i < 4; i++)
        out[(size_t)(n0 + ty + i * 8) * K + k0 + tx] = (bf16_t)tile[tx][ty + i * 8];
}

// ---------------------------------------------------------------------------
// G-prep: G[j][p*64+q] = sum_o Wf1[(p*64+q)*64 + o] * Wf2[o*2+j]
//         c[j] = sum_o bf1[o]*Wf2[o*2+j] + bf2[j]
// ---------------------------------------------------------------------------
__global__ __launch_bounds__(256) void k_prepG(
    const float* __restrict__ Wf1, const float* __restrict__ bf1v,
    const float* __restrict__ Wf2, const float* __restrict__ bf2v,
    float* __restrict__ G, float* __restrict__ c)
{
    const int i = blockIdx.x * 256 + threadIdx.x;   // 0..4095
    float a0 = 0.f, a1 = 0.f;
    #pragma unroll 8
    for (int o = 0; o < 64; o++) {
        float w = Wf1[(size_t)i * 64 + o];
        a0 = fmaf(w, Wf2[o * 2 + 0], a0);
        a1 = fmaf(w, Wf2[o * 2 + 1], a1);
    }
    G[i]        = a0;
    G[4096 + i] = a1;
    if (i < 2) {
        float s = bf2v[i];
        for (int o = 0; o < 64; o++) s = fmaf(bf1v[o], Wf2[o * 2 + i], s);
        c[i] = s;
    }
}

// ---------------------------------------------------------------------------
// GEMM1: H = relu(X @ Wb + bb)  -> bf16   [16384,1024]x[1024,512]
// 128x128 tile, BK=32, 256 thr (4 waves), wave computes 64x64 via 4x4 MFMAs.
// X fp32 converted inline; WT pre-converted bf16 [N][K].
// ---------------------------------------------------------------------------
__global__ __launch_bounds__(256) void k_gemm1(
    const float* __restrict__ X1, const float* __restrict__ X2,
    const bf16_t* __restrict__ WT1, const bf16_t* __restrict__ WT2,
    const float* __restrict__ bias1, const float* __restrict__ bias2,
    bf16_t* __restrict__ H1, bf16_t* __restrict__ H2)
{
    const float*  X    = blockIdx.z ? X2    : X1;
    const bf16_t* WT   = blockIdx.z ? WT2   : WT1;
    const float*  bias = blockIdx.z ? bias2 : bias1;
    bf16_t*       H    = blockIdx.z ? H2    : H1;

    const int m0 = blockIdx.y * 128;
    const int n0 = blockIdx.x * 128;

    // 40 = 32 + 8 pad: row stride 80 B (16B-aligned, 20-bank skew)
    __shared__ bf16_t As[128][40];
    __shared__ bf16_t Bs[128][40];

    const int tid  = threadIdx.x;
    const int lane = tid & 63;
    const int wave = tid >> 6;
    const int wr   = (wave >> 1) * 64;
    const int wc   = (wave & 1) * 64;
    const int l15  = lane & 15;
    const int lk   = (lane >> 4) * 8;

    f32x4 acc[4][4] = {};

    for (int k0 = 0; k0 < DIN; k0 += 32) {
        // stage A: 128 rows x 32 fp32 -> bf16 (1024 float4 chunks / 256 thr)
        #pragma unroll
        for (int i = 0; i < 4; i++) {
            int c = tid + i * 256;
            int row = c >> 3, cl = c & 7;
            float4 v = *reinterpret_cast<const float4*>(
                &X[(size_t)(m0 + row) * DIN + k0 + cl * 4]);
            bf16x4 bv;
            bv[0] = (bf16_t)v.x; bv[1] = (bf16_t)v.y;
            bv[2] = (bf16_t)v.z; bv[3] = (bf16_t)v.w;
            *reinterpret_cast<bf16x4*>(&As[row][cl * 4]) = bv;
        }
        // stage B: 128 n-rows x 32 k bf16 (512 16B chunks / 256 thr)
        #pragma unroll
        for (int i = 0; i < 2; i++) {
            int c = tid + i * 256;
            int n = c >> 2, cl = c & 3;
            *reinterpret_cast<uint4*>(&Bs[n][cl * 8]) =
                *reinterpret_cast<const uint4*>(&WT[(size_t)(n0 + n) * DIN + k0 + cl * 8]);
        }
        __syncthreads();
        bf16x8 af[4], bfv[4];
        #pragma unroll
        for (int mi = 0; mi < 4; mi++)
            af[mi] = *reinterpret_cast<const bf16x8*>(&As[wr + mi * 16 + l15][lk]);
        #pragma unroll
        for (int ni = 0; ni < 4; ni++)
            bfv[ni] = *reinterpret_cast<const bf16x8*>(&Bs[wc + ni * 16 + l15][lk]);
        #pragma unroll
        for (int mi = 0; mi < 4; mi++)
            #pragma unroll
            for (int ni = 0; ni < 4; ni++)
                acc[mi][ni] = __builtin_amdgcn_mfma_f32_16x16x32_bf16(
                    af[mi], bfv[ni], acc[mi][ni], 0, 0, 0);
        __syncthreads();
    }

    // epilogue: +bias, relu, bf16 store. D: row=(lane>>4)*4+r, col=lane&15
    #pragma unroll
    for (int ni = 0; ni < 4; ni++) {
        int col = n0 + wc + ni * 16 + l15;
        float bv = bias[col];
        #pragma unroll
        for (int mi = 0; mi < 4; mi++) {
            int rbase = m0 + wr + mi * 16 + (lane >> 4) * 4;
            #pragma unroll
            for (int r = 0; r < 4; r++) {
                float v = acc[mi][ni][r] + bv;
                v = fmaxf(v, 0.0f);
                H[(size_t)(rbase + r) * HID + col] = (bf16_t)v;
            }
        }
    }
}

// ---------------------------------------------------------------------------
// GEMM2: F = H @ Wc + bc -> fp32   [16384,512]x[512,64]
// 128x64 tile, 256 thr (4 waves), wave computes 32x64 via 2x4 MFMAs.
// ---------------------------------------------------------------------------
__global__ __launch_bounds__(256) void k_gemm2(
    const bf16_t* __restrict__ Ha, const bf16_t* __restrict__ Hb,
    const bf16_t* __restrict__ WTa, const bf16_t* __restrict__ WTb,
    const float* __restrict__ biasa, const float* __restrict__ biasb,
    float* __restrict__ Fa, float* __restrict__ Fb)
{
    const bf16_t* Hh   = blockIdx.z ? Hb    : Ha;
    const bf16_t* WT   = blockIdx.z ? WTb   : WTa;
    const float*  bias = blockIdx.z ? biasb : biasa;
    float*        F    = blockIdx.z ? Fb    : Fa;

    const int m0 = blockIdx.x * 128;
    __shared__ bf16_t As[128][40];
    __shared__ bf16_t Bs[64][40];

    const int tid  = threadIdx.x;
    const int lane = tid & 63;
    const int wave = tid >> 6;
    const int wr   = wave * 32;
    const int l15  = lane & 15;
    const int lk   = (lane >> 4) * 8;

    f32x4 acc[2][4] = {};

    for (int k0 = 0; k0 < HID; k0 += 32) {
        #pragma unroll
        for (int i = 0; i < 2; i++) {
            int c = tid + i * 256;
            int row = c >> 2, cl = c & 3;
            *reinterpret_cast<uint4*>(&As[row][cl * 8]) =
                *reinterpret_cast<const uint4*>(&Hh[(size_t)(m0 + row) * HID + k0 + cl * 8]);
        }
        {
            int n = tid >> 2, cl = tid & 3;   // 256 chunks, 1 per thread
            *reinterpret_cast<uint4*>(&Bs[n][cl * 8]) =
                *reinterpret_cast<const uint4*>(&WT[(size_t)n * HID + k0 + cl * 8]);
        }
        __syncthreads();
        bf16x8 af[2], bfv[4];
        #pragma unroll
        for (int mi = 0; mi < 2; mi++)
            af[mi] = *reinterpret_cast<const bf16x8*>(&As[wr + mi * 16 + l15][lk]);
        #pragma unroll
        for (int ni = 0; ni < 4; ni++)
            bfv[ni] = *reinterpret_cast<const bf16x8*>(&Bs[ni * 16 + l15][lk]);
        #pragma unroll
        for (int mi = 0; mi < 2; mi++)
            #pragma unroll
            for (int ni = 0; ni < 4; ni++)
                acc[mi][ni] = __builtin_amdgcn_mfma_f32_16x16x32_bf16(
                    af[mi], bfv[ni], acc[mi][ni], 0, 0, 0);
        __syncthreads();
    }

    #pragma unroll
    for (int ni = 0; ni < 4; ni++) {
        int col = ni * 16 + l15;
        float bv = bias[col];
        #pragma unroll
        for (int mi = 0; mi < 2; mi++) {
            int rbase = m0 + wr + mi * 16 + (lane >> 4) * 4;
            #pragma unroll
            for (int r = 0; r < 4; r++)
                F[(size_t)(rbase + r) * COMP + col] = acc[mi][ni][r] + bv;
        }
    }
}

// ---------------------------------------------------------------------------
// bilinear: out[b][j] = f2[b] . G_j . f1[b]^T + c[j]
// wave per sample (lane = q); G (32 KB) in LDS, uniform-index broadcast.
// grid 1024 x 256thr: 4 waves/block x 4 samples/wave = 16384.
// ---------------------------------------------------------------------------
__global__ __launch_bounds__(256) void k_bilinear(
    const float* __restrict__ f1, const float* __restrict__ f2,
    const float* __restrict__ G, const float* __restrict__ c,
    float* __restrict__ out)
{
    __shared__ float Gs[2][4096];
    const int tid = threadIdx.x;
    for (int i = tid; i < 2048; i += 256)
        reinterpret_cast<float4*>(&Gs[0][0])[i] =
            reinterpret_cast<const float4*>(G)[i];
    const float c0 = c[0], c1 = c[1];
    __syncthreads();

    const int lane = tid & 63;
    const int wave = tid >> 6;
    const int base = (blockIdx.x * 4 + wave) * 4;

    for (int s = 0; s < 4; s++) {
        const int b = base + s;
        const float f1q = f1[(size_t)b * 64 + lane];
        const float f2q = f2[(size_t)b * 64 + lane];
        float a0 = 0.f, a1 = 0.f;
        #pragma unroll 8
        for (int p = 0; p < 64; p++) {
            float s2 = __shfl(f2q, p);
            a0 = fmaf(s2, Gs[0][p * 64 + lane], a0);
            a1 = fmaf(s2, Gs[1][p * 64 + lane], a1);
        }
        a0 *= f1q;
        a1 *= f1q;
        #pragma unroll
        for (int off = 32; off > 0; off >>= 1) {
            a0 += __shfl_xor(a0, off);
            a1 += __shfl_xor(a1, off);
        }
        if (lane == 0) {
            out[(size_t)b * 2 + 0] = a0 + c0;
            out[(size_t)b * 2 + 1] = a1 + c1;
        }
    }
}

// ---------------------------------------------------------------------------
extern "C" void kernel_launch(void* const* d_in, const int* in_sizes, int n_in,
                              void* d_out, int out_size, void* d_ws, size_t ws_size,
                              hipStream_t stream)
{
    const float* x1  = (const float*)d_in[0];
    const float* x2  = (const float*)d_in[1];
    const float* Wb1 = (const float*)d_in[2];
    const float* bb1 = (const float*)d_in[3];
    const float* Wb2 = (const float*)d_in[4];
    const float* bb2 = (const float*)d_in[5];
    const float* Wc1 = (const float*)d_in[6];
    const float* bc1 = (const float*)d_in[7];
    const float* Wc2 = (const float*)d_in[8];
    const float* bc2 = (const float*)d_in[9];
    const float* Wf1 = (const float*)d_in[10];
    const float* bf1v = (const float*)d_in[11];
    const float* Wf2 = (const float*)d_in[12];
    const float* bf2v = (const float*)d_in[13];
    float* out = (float*)d_out;

    // workspace carve-up (~42.3 MB total; all sizes 16B-multiples)
    char* ws = (char*)d_ws;
    bf16_t* wbt1 = (bf16_t*)ws; ws += (size_t)HID * DIN * 2;     // 1 MB
    bf16_t* wbt2 = (bf16_t*)ws; ws += (size_t)HID * DIN * 2;     // 1 MB
    bf16_t* wct1 = (bf16_t*)ws; ws += (size_t)COMP * HID * 2;    // 64 KB
    bf16_t* wct2 = (bf16_t*)ws; ws += (size_t)COMP * HID * 2;    // 64 KB
    bf16_t* h1   = (bf16_t*)ws; ws += (size_t)B_SZ * HID * 2;    // 16 MB
    bf16_t* h2   = (bf16_t*)ws; ws += (size_t)B_SZ * HID * 2;    // 16 MB
    float*  f1   = (float*)ws;  ws += (size_t)B_SZ * COMP * 4;   // 4 MB
    float*  f2   = (float*)ws;  ws += (size_t)B_SZ * COMP * 4;   // 4 MB
    float*  G    = (float*)ws;  ws += (size_t)2 * 4096 * 4;      // 32 KB
    float*  c    = (float*)ws;  ws += 256;

    k_transpose<<<dim3(HID / 32, DIN / 32, 2), dim3(32, 8), 0, stream>>>(
        Wb1, wbt1, Wb2, wbt2, DIN, HID);
    k_transpose<<<dim3(COMP / 32, HID / 32, 2), dim3(32, 8), 0, stream>>>(
        Wc1, wct1, Wc2, wct2, HID, COMP);
    k_prepG<<<16, 256, 0, stream>>>(Wf1, bf1v, Wf2, bf2v, G, c);
    k_gemm1<<<dim3(HID / 128, B_SZ / 128, 2), 256, 0, stream>>>(
        x1, x2, wbt1, wbt2, bb1, bb2, h1, h2);
    k_gemm2<<<dim3(B_SZ / 128, 1, 2), 256, 0, stream>>>(
        h1, h2, wct1, wct2, bc1, bc2, f1, f2);
    k_bilinear<<<1024, 256, 0, stream>>>(f1, f2, G, c, out);
}

// Round 2
// 276.854 us; speedup vs baseline: 1.0181x; 1.0181x over previous
//
#include <hip/hip_runtime.h>

#define B_SZ 16384
#define DIN  1024
#define HID  512
#define COMP 64

typedef __bf16 bf16_t;
typedef __bf16 bf16x4 __attribute__((ext_vector_type(4)));
typedef __bf16 bf16x8 __attribute__((ext_vector_type(8)));
typedef float  f32x4  __attribute__((ext_vector_type(4)));

// async global->LDS, 16B per lane. LDS dest is wave-uniform base + lane*16:
// the chunk index must be lane-contiguous within each wave.
__device__ __forceinline__ void gl2lds16(const bf16_t* g, bf16_t* l) {
    __builtin_amdgcn_global_load_lds(
        (const __attribute__((address_space(1))) void*)g,
        (__attribute__((address_space(3))) void*)l, 16, 0, 0);
}

// ---------------------------------------------------------------------------
// fused prep: blocks [0,1024) transpose Wb (1024x512 -> 512x1024 bf16, x2)
//             blocks [1024,1088) transpose Wc (512x64 -> 64x512 bf16, x2)
//             blocks [1088,1104) prepG: G[j][i] = sum_o Wf1[i*64+o]*Wf2[o*2+j]
// ---------------------------------------------------------------------------
__global__ __launch_bounds__(256) void k_prep(
    const float* __restrict__ Wb1, const float* __restrict__ Wb2,
    bf16_t* __restrict__ wbt1, bf16_t* __restrict__ wbt2,
    const float* __restrict__ Wc1, const float* __restrict__ Wc2,
    bf16_t* __restrict__ wct1, bf16_t* __restrict__ wct2,
    const float* __restrict__ Wf1, const float* __restrict__ bf1v,
    const float* __restrict__ Wf2, const float* __restrict__ bf2v,
    float* __restrict__ G, float* __restrict__ c)
{
    const int bid = blockIdx.x, tid = threadIdx.x;
    __shared__ float tile[32][33];
    const int tx = tid & 31, ty = tid >> 5;

    if (bid < 1024) {                     // Wb transpose: K=1024, N=512
        const int z = bid >> 9, t = bid & 511;
        const float* in  = z ? Wb2  : Wb1;
        bf16_t*      out = z ? wbt2 : wbt1;
        const int n0 = (t & 15) * 32, k0 = (t >> 4) * 32;
        #pragma unroll
        for (int i = 0; i < 4; i++)
            tile[ty + i * 8][tx] = in[(size_t)(k0 + ty + i * 8) * HID + n0 + tx];
        __syncthreads();
        #pragma unroll
        for (int i = 0; i < 4; i++)
            out[(size_t)(n0 + ty + i * 8) * DIN + k0 + tx] = (bf16_t)tile[tx][ty + i * 8];
    } else if (bid < 1088) {              // Wc transpose: K=512, N=64
        const int l = bid - 1024;
        const int z = l >> 5, t = l & 31;
        const float* in  = z ? Wc2  : Wc1;
        bf16_t*      out = z ? wct2 : wct1;
        const int n0 = (t & 1) * 32, k0 = (t >> 1) * 32;
        #pragma unroll
        for (int i = 0; i < 4; i++)
            tile[ty + i * 8][tx] = in[(size_t)(k0 + ty + i * 8) * COMP + n0 + tx];
        __syncthreads();
        #pragma unroll
        for (int i = 0; i < 4; i++)
            out[(size_t)(n0 + ty + i * 8) * HID + k0 + tx] = (bf16_t)tile[tx][ty + i * 8];
    } else {                              // prepG
        const int i = (bid - 1088) * 256 + tid;   // 0..4095
        float a0 = 0.f, a1 = 0.f;
        #pragma unroll 8
        for (int o = 0; o < 64; o++) {
            float w = Wf1[(size_t)i * 64 + o];
            a0 = fmaf(w, Wf2[o * 2 + 0], a0);
            a1 = fmaf(w, Wf2[o * 2 + 1], a1);
        }
        G[i]        = a0;
        G[4096 + i] = a1;
        if (i < 2) {
            float s = bf2v[i];
            for (int o = 0; o < 64; o++) s = fmaf(bf1v[o], Wf2[o * 2 + i], s);
            c[i] = s;
        }
    }
}

// ---------------------------------------------------------------------------
// GEMM1: H = relu(X @ Wb + bb) -> bf16  [16384,1024]x[1024,512]
// 128x128 tile, BK=32, 256 thr. B staged via global_load_lds (16B);
// A staged fp32->bf16 via VGPR convert. Unpadded LDS (m97 layout).
// ---------------------------------------------------------------------------
__global__ __launch_bounds__(256) void k_gemm1(
    const float* __restrict__ X1, const float* __restrict__ X2,
    const bf16_t* __restrict__ WT1, const bf16_t* __restrict__ WT2,
    const float* __restrict__ bias1, const float* __restrict__ bias2,
    bf16_t* __restrict__ H1, bf16_t* __restrict__ H2)
{
    const float*  X    = blockIdx.z ? X2    : X1;
    const bf16_t* WT   = blockIdx.z ? WT2   : WT1;
    const float*  bias = blockIdx.z ? bias2 : bias1;
    bf16_t*       H    = blockIdx.z ? H2    : H1;

    const int m0 = blockIdx.y * 128;
    const int n0 = blockIdx.x * 128;

    __shared__ bf16_t As[128 * 32];   // 8 KB, unpadded
    __shared__ bf16_t Bs[128 * 32];   // 8 KB, unpadded (global_load_lds dest)

    const int tid  = threadIdx.x;
    const int lane = tid & 63;
    const int wave = tid >> 6;
    const int wr   = (wave >> 1) * 64;
    const int wc   = (wave & 1) * 64;
    const int l15  = lane & 15;
    const int lk   = (lane >> 4) * 8;

    f32x4 acc[4][4] = {};

    for (int k0 = 0; k0 < DIN; k0 += 32) {
        // B: 512 x 16B chunks; chunk c -> n=c>>2, khalf=(c&3)*8.
        // c = i*256 + tid keeps lanes contiguous per (issue, wave).
        #pragma unroll
        for (int i = 0; i < 2; i++) {
            int c = i * 256 + tid;
            int n = c >> 2, kh = (c & 3) * 8;
            gl2lds16(&WT[(size_t)(n0 + n) * DIN + k0 + kh], &Bs[c * 8]);
        }
        // A: 1024 float4 chunks (8 lanes/row -> 128B segments), cvt, b64 write
        #pragma unroll
        for (int i = 0; i < 4; i++) {
            int c = i * 256 + tid;
            int row = c >> 3, q = c & 7;
            float4 v = *reinterpret_cast<const float4*>(
                &X[(size_t)(m0 + row) * DIN + k0 + q * 4]);
            bf16x4 bv;
            bv[0] = (bf16_t)v.x; bv[1] = (bf16_t)v.y;
            bv[2] = (bf16_t)v.z; bv[3] = (bf16_t)v.w;
            *reinterpret_cast<bf16x4*>(&As[row * 32 + q * 4]) = bv;
        }
        __syncthreads();

        bf16x8 af[4], bfv[4];
        #pragma unroll
        for (int mi = 0; mi < 4; mi++)
            af[mi] = *reinterpret_cast<const bf16x8*>(&As[(wr + mi * 16 + l15) * 32 + lk]);
        #pragma unroll
        for (int ni = 0; ni < 4; ni++)
            bfv[ni] = *reinterpret_cast<const bf16x8*>(&Bs[(wc + ni * 16 + l15) * 32 + lk]);
        #pragma unroll
        for (int mi = 0; mi < 4; mi++)
            #pragma unroll
            for (int ni = 0; ni < 4; ni++)
                acc[mi][ni] = __builtin_amdgcn_mfma_f32_16x16x32_bf16(
                    af[mi], bfv[ni], acc[mi][ni], 0, 0, 0);
        __syncthreads();
    }

    // epilogue: +bias, relu, bf16. C/D: col=lane&15, row=(lane>>4)*4+r
    #pragma unroll
    for (int ni = 0; ni < 4; ni++) {
        int col = n0 + wc + ni * 16 + l15;
        float bv = bias[col];
        #pragma unroll
        for (int mi = 0; mi < 4; mi++) {
            int rbase = m0 + wr + mi * 16 + (lane >> 4) * 4;
            #pragma unroll
            for (int r = 0; r < 4; r++) {
                float v = acc[mi][ni][r] + bv;
                v = fmaxf(v, 0.0f);
                H[(size_t)(rbase + r) * HID + col] = (bf16_t)v;
            }
        }
    }
}

// ---------------------------------------------------------------------------
// GEMM2: F = H @ Wc + bc -> fp32  [16384,512]x[512,64]
// 64x64 tile, 512 blocks (2/CU), both operands via global_load_lds.
// ---------------------------------------------------------------------------
__global__ __launch_bounds__(256) void k_gemm2(
    const bf16_t* __restrict__ Ha, const bf16_t* __restrict__ Hb,
    const bf16_t* __restrict__ WTa, const bf16_t* __restrict__ WTb,
    const float* __restrict__ biasa, const float* __restrict__ biasb,
    float* __restrict__ Fa, float* __restrict__ Fb)
{
    const bf16_t* Hh   = blockIdx.z ? Hb    : Ha;
    const bf16_t* WT   = blockIdx.z ? WTb   : WTa;
    const float*  bias = blockIdx.z ? biasb : biasa;
    float*        F    = blockIdx.z ? Fb    : Fa;

    const int m0 = blockIdx.x * 64;
    __shared__ bf16_t As[64 * 32];    // 4 KB
    __shared__ bf16_t Bs[64 * 32];    // 4 KB

    const int tid  = threadIdx.x;
    const int lane = tid & 63;
    const int wave = tid >> 6;
    const int wr   = wave * 16;
    const int l15  = lane & 15;
    const int lk   = (lane >> 4) * 8;

    f32x4 acc[4] = {};

    for (int k0 = 0; k0 < HID; k0 += 32) {
        // 256 chunks each: chunk c -> row=c>>2, khalf=(c&3)*8 (64B/row segs)
        {
            int c = tid;
            int n = c >> 2, kh = (c & 3) * 8;
            gl2lds16(&WT[(size_t)n * HID + k0 + kh], &Bs[c * 8]);
            gl2lds16(&Hh[(size_t)(m0 + n) * HID + k0 + kh], &As[c * 8]);
        }
        __syncthreads();

        bf16x8 af = *reinterpret_cast<const bf16x8*>(&As[(wr + l15) * 32 + lk]);
        bf16x8 bfv[4];
        #pragma unroll
        for (int ni = 0; ni < 4; ni++)
            bfv[ni] = *reinterpret_cast<const bf16x8*>(&Bs[(ni * 16 + l15) * 32 + lk]);
        #pragma unroll
        for (int ni = 0; ni < 4; ni++)
            acc[ni] = __builtin_amdgcn_mfma_f32_16x16x32_bf16(af, bfv[ni], acc[ni], 0, 0, 0);
        __syncthreads();
    }

    #pragma unroll
    for (int ni = 0; ni < 4; ni++) {
        int col = ni * 16 + l15;
        float bv = bias[col];
        int rbase = m0 + wr + (lane >> 4) * 4;
        #pragma unroll
        for (int r = 0; r < 4; r++)
            F[(size_t)(rbase + r) * COMP + col] = acc[ni][r] + bv;
    }
}

// ---------------------------------------------------------------------------
// bilinear: out[b][j] = f2[b] . G_j . f1[b]^T + c[j]
// ---------------------------------------------------------------------------
__global__ __launch_bounds__(256) void k_bilinear(
    const float* __restrict__ f1, const float* __restrict__ f2,
    const float* __restrict__ G, const float* __restrict__ c,
    float* __restrict__ out)
{
    __shared__ float Gs[2][4096];
    const int tid = threadIdx.x;
    for (int i = tid; i < 2048; i += 256)
        reinterpret_cast<float4*>(&Gs[0][0])[i] =
            reinterpret_cast<const float4*>(G)[i];
    const float c0 = c[0], c1 = c[1];
    __syncthreads();

    const int lane = tid & 63;
    const int wave = tid >> 6;
    const int base = (blockIdx.x * 4 + wave) * 4;

    for (int s = 0; s < 4; s++) {
        const int b = base + s;
        const float f1q = f1[(size_t)b * 64 + lane];
        const float f2q = f2[(size_t)b * 64 + lane];
        float a0 = 0.f, a1 = 0.f;
        #pragma unroll 8
        for (int p = 0; p < 64; p++) {
            float s2 = __shfl(f2q, p);
            a0 = fmaf(s2, Gs[0][p * 64 + lane], a0);
            a1 = fmaf(s2, Gs[1][p * 64 + lane], a1);
        }
        a0 *= f1q;
        a1 *= f1q;
        #pragma unroll
        for (int off = 32; off > 0; off >>= 1) {
            a0 += __shfl_xor(a0, off);
            a1 += __shfl_xor(a1, off);
        }
        if (lane == 0) {
            out[(size_t)b * 2 + 0] = a0 + c0;
            out[(size_t)b * 2 + 1] = a1 + c1;
        }
    }
}

// ---------------------------------------------------------------------------
extern "C" void kernel_launch(void* const* d_in, const int* in_sizes, int n_in,
                              void* d_out, int out_size, void* d_ws, size_t ws_size,
                              hipStream_t stream)
{
    const float* x1  = (const float*)d_in[0];
    const float* x2  = (const float*)d_in[1];
    const float* Wb1 = (const float*)d_in[2];
    const float* bb1 = (const float*)d_in[3];
    const float* Wb2 = (const float*)d_in[4];
    const float* bb2 = (const float*)d_in[5];
    const float* Wc1 = (const float*)d_in[6];
    const float* bc1 = (const float*)d_in[7];
    const float* Wc2 = (const float*)d_in[8];
    const float* bc2 = (const float*)d_in[9];
    const float* Wf1 = (const float*)d_in[10];
    const float* bf1v = (const float*)d_in[11];
    const float* Wf2 = (const float*)d_in[12];
    const float* bf2v = (const float*)d_in[13];
    float* out = (float*)d_out;

    // workspace carve-up (~42.3 MB, same as round-1 known-safe footprint)
    char* ws = (char*)d_ws;
    bf16_t* wbt1 = (bf16_t*)ws; ws += (size_t)HID * DIN * 2;
    bf16_t* wbt2 = (bf16_t*)ws; ws += (size_t)HID * DIN * 2;
    bf16_t* wct1 = (bf16_t*)ws; ws += (size_t)COMP * HID * 2;
    bf16_t* wct2 = (bf16_t*)ws; ws += (size_t)COMP * HID * 2;
    bf16_t* h1   = (bf16_t*)ws; ws += (size_t)B_SZ * HID * 2;
    bf16_t* h2   = (bf16_t*)ws; ws += (size_t)B_SZ * HID * 2;
    float*  f1   = (float*)ws;  ws += (size_t)B_SZ * COMP * 4;
    float*  f2   = (float*)ws;  ws += (size_t)B_SZ * COMP * 4;
    float*  G    = (float*)ws;  ws += (size_t)2 * 4096 * 4;
    float*  c    = (float*)ws;  ws += 256;

    k_prep<<<1104, 256, 0, stream>>>(Wb1, Wb2, wbt1, wbt2,
                                     Wc1, Wc2, wct1, wct2,
                                     Wf1, bf1v, Wf2, bf2v, G, c);
    k_gemm1<<<dim3(HID / 128, B_SZ / 128, 2), 256, 0, stream>>>(
        x1, x2, wbt1, wbt2, bb1, bb2, h1, h2);
    k_gemm2<<<dim3(B_SZ / 64, 1, 2), 256, 0, stream>>>(
        h1, h2, wct1, wct2, bc1, bc2, f1, f2);
    k_bilinear<<<1024, 256, 0, stream>>>(f1, f2, G, c, out);
}